// Round 4
// baseline (291.870 us; speedup 1.0000x reference)
//
#include <hip/hip_runtime.h>
#include <stdint.h>

#define B_   16
#define T_   2048
#define D_   1024
#define TT_  2046
#define W_   682            // MAX_WORDS
#define BW_  (B_ * W_)      // 10912
#define NMUT 64
#define NBIN 32

typedef __attribute__((ext_vector_type(8)))  short s8b;    // 8 bf16 (4 VGPRs)
typedef __attribute__((ext_vector_type(4)))  float f32x4;
typedef __attribute__((ext_vector_type(16))) float f32x16;

__device__ inline short f2bf(float f) {                   // RNE f32->bf16
    uint32_t u = __builtin_bit_cast(uint32_t, f);
    u += 0x7FFFu + ((u >> 16) & 1u);
    return (short)(u >> 16);
}

__device__ inline float fast_tanh(float x) {
    float xc = fminf(fmaxf(x, -15.f), 15.f);
    float e  = __expf(2.f * xc);
    return 1.f - 2.f / (e + 1.f);
}

__device__ inline void gload_lds16(const void* g, void* l) {
    __builtin_amdgcn_global_load_lds(
        (const __attribute__((address_space(1))) uint32_t*)g,
        (__attribute__((address_space(3))) uint32_t*)l, 16, 0, 0);
}

// ---------------------------------------------------------------------------
// K0: merged prep.
//   blocks [0,16)        : word-boundary scan (one block per batch row)
//   blocks [16,1040)     : dense_w fp32->bf16
//   blocks [1040,1104)   : out_w  fp32->bf16 into Bcat rows 0..63
//   blocks [1104,1136)   : W_eff fold -> Bcat rows 64..95 (+ b_eff)
// ---------------------------------------------------------------------------
__global__ __launch_bounds__(256) void k_prep(const int* __restrict__ ws,
                                              const float* __restrict__ dw,
                                              const float* __restrict__ ow,
                                              const float* __restrict__ ob,
                                              const float* __restrict__ bw,
                                              const float* __restrict__ bb,
                                              int* __restrict__ starts,
                                              int* __restrict__ nwords,
                                              short* __restrict__ dwb,
                                              short* __restrict__ Bcat,
                                              float* __restrict__ beff) {
    __shared__ float smem[NMUT];
    int blk = blockIdx.x;
    int tid = threadIdx.x;

    if (blk < 16) {
        int b = blk;
        const int* row = ws + (size_t)b * TT_;
        int vals[8], incl[8];
        int p = 0;
        int t0 = tid * 8;
#pragma unroll
        for (int i = 0; i < 8; ++i) {
            int t = t0 + i;
            int v = (t < TT_) ? row[t] : 0;
            vals[i] = v;
            p += v;
            incl[i] = p;
        }
        int tot = p;
        int lane = tid & 63;
        int x = tot;
#pragma unroll
        for (int off = 1; off < 64; off <<= 1) {
            int v = __shfl_up(x, off);
            if (lane >= off) x += v;
        }
        int* wsum = (int*)smem;
        int wid = tid >> 6;
        if (lane == 63) wsum[wid] = x;
        __syncthreads();
        int wbase = 0;
        for (int q = 0; q < wid; ++q) wbase += wsum[q];
        int excl = wbase + x - tot;
        int* st = starts + (size_t)b * (W_ + 1);
#pragma unroll
        for (int i = 0; i < 8; ++i) {
            if (vals[i]) {
                int w = excl + incl[i] - 1;
                if (w <= W_) st[w] = t0 + i;
            }
        }
        if (tid == 0) {
            int total = wsum[0] + wsum[1] + wsum[2] + wsum[3];
            int nw = total < W_ ? total : W_;
            nwords[b] = nw;
            if (total <= W_) st[total] = TT_;
        }
    } else if (blk < 16 + 1024) {
        int i = (blk - 16) * 256 + tid;
        float4 v = ((const float4*)dw)[i];
        short4 o;
        o.x = f2bf(v.x); o.y = f2bf(v.y); o.z = f2bf(v.z); o.w = f2bf(v.w);
        *(short4*)(dwb + (size_t)i * 4) = o;
    } else if (blk < 16 + 1024 + 64) {
        int i = (blk - 1040) * 256 + tid;
        float4 v = ((const float4*)ow)[i];
        short4 o;
        o.x = f2bf(v.x); o.y = f2bf(v.y); o.z = f2bf(v.z); o.w = f2bf(v.w);
        *(short4*)(Bcat + (size_t)i * 4) = o;
    } else {
        int j = blk - 1104;
        if (tid < NMUT) smem[tid] = bw[(size_t)j * (D_ + NMUT) + tid];
        __syncthreads();
        for (int k = tid; k < D_; k += 256) {
            float acc = bw[(size_t)j * (D_ + NMUT) + NMUT + k];
#pragma unroll 8
            for (int c = 0; c < NMUT; ++c)
                acc = fmaf(smem[c], ow[(size_t)c * D_ + k], acc);
            Bcat[(size_t)(NMUT + j) * D_ + k] = f2bf(acc);
        }
        if (tid == 0) {
            float acc = bb[j];
            for (int c = 0; c < NMUT; ++c) acc = fmaf(smem[c], ob[c], acc);
            beff[j] = acc;
        }
    }
}

// ---------------------------------------------------------------------------
// K2: word feature sums -> bf16. 2 words per block, single fused token loop
// (independent row loads -> MLP; accumulator picked by t < m1).
// ---------------------------------------------------------------------------
__global__ __launch_bounds__(256) void k_wf(const float* __restrict__ feat,
                                            const int* __restrict__ starts,
                                            const int* __restrict__ nwords,
                                            short* __restrict__ wf) {
    int blk = blockIdx.x;                 // 0 .. BW_/2-1
    int b  = blk / (W_ / 2);
    int w0 = (blk - b * (W_ / 2)) * 2;
    int w1 = w0 + 1;
    int tid = threadIdx.x;
    int nw = nwords[b];
    const int* st = starts + (size_t)b * (W_ + 1);

    bool v0 = w0 < nw, v1 = w1 < nw;
    int s0 = v0 ? st[w0] : 0;
    int m1 = v0 ? st[w0 + 1] : 0;         // end of word0 / start of word1
    int e1 = v1 ? st[w1 + 1] : m1;

    float4 a0 = make_float4(0.f, 0.f, 0.f, 0.f);
    float4 a1 = make_float4(0.f, 0.f, 0.f, 0.f);
    const float4* base = (const float4*)(feat + ((size_t)b * T_ + 1) * D_) + tid;
    for (int t = s0; t < e1; ++t) {
        float4 v = base[(size_t)t * (D_ / 4)];
        if (t < m1) { a0.x += v.x; a0.y += v.y; a0.z += v.z; a0.w += v.w; }
        else        { a1.x += v.x; a1.y += v.y; a1.z += v.z; a1.w += v.w; }
    }
    if (!v0) a0 = make_float4(1.f, 1.f, 1.f, 1.f);
    if (!v1) a1 = make_float4(1.f, 1.f, 1.f, 1.f);

    short4 o0, o1;
    o0.x = f2bf(a0.x); o0.y = f2bf(a0.y); o0.z = f2bf(a0.z); o0.w = f2bf(a0.w);
    o1.x = f2bf(a1.x); o1.y = f2bf(a1.y); o1.z = f2bf(a1.z); o1.w = f2bf(a1.w);
    size_t row0 = (size_t)b * W_ + w0;
    *(short4*)(wf + row0 * D_ + tid * 4)        = o0;
    *(short4*)(wf + (row0 + 1) * D_ + tid * 4)  = o1;
}

// ---------------------------------------------------------------------------
// K4: h = tanh(wf . dense_w^T + db) via MFMA 32x32x16 bf16.
// 128x128 tile, BK=64 (two 32-k sub-buffers). Each wave: 64x64 = 2x2 of 32x32.
// A/B frag: m|n = lane&31, k = (lane>>5)*8 + j.
// C/D: col = lane&31, row = (reg&3) + 8*(reg>>2) + 4*(lane>>5)  [m74/m101]
// ---------------------------------------------------------------------------
__global__ __launch_bounds__(256) void k_gemm1(const short* __restrict__ wf,
                                               const short* __restrict__ dwb,
                                               const float* __restrict__ db,
                                               short* __restrict__ h) {
    __shared__ short As[2][128 * 32];
    __shared__ short Bs[2][128 * 32];
    int tid  = threadIdx.x;
    int lane = tid & 63;
    int w    = tid >> 6;
    int wm = w >> 1, wn = w & 1;
    int bm = blockIdx.x * 128;
    int bn = blockIdx.y * 128;

    int l31 = lane & 31;
    int lh  = lane >> 5;         // k-half for A/B frags, row-half for C

    int srow = lane >> 2;        // staging: 16 rows per 1KB wave chunk
    int scol = (lane & 3) * 8;

    f32x16 acc[2][2];
#pragma unroll
    for (int i = 0; i < 2; ++i)
#pragma unroll
        for (int j = 0; j < 2; ++j)
#pragma unroll
            for (int r = 0; r < 16; ++r) acc[i][j][r] = 0.f;

    for (int kt = 0; kt < D_; kt += 64) {
#pragma unroll
        for (int hh = 0; hh < 2; ++hh) {
#pragma unroll
            for (int p = 0; p < 2; ++p) {
                int chunk = w * 2 + p;               // 0..7, 16 rows each
                int arow = bm + chunk * 16 + srow;
                arow = arow < BW_ ? arow : BW_ - 1;  // clamp tail
                gload_lds16(wf + (size_t)arow * D_ + kt + hh * 32 + scol,
                            &As[hh][chunk * 512]);
                int brow = bn + chunk * 16 + srow;
                gload_lds16(dwb + (size_t)brow * D_ + kt + hh * 32 + scol,
                            &Bs[hh][chunk * 512]);
            }
        }
        __syncthreads();
#pragma unroll
        for (int hh = 0; hh < 2; ++hh) {
#pragma unroll
            for (int c = 0; c < 2; ++c) {            // k-chunk of 16
                int koff = c * 16 + lh * 8;
                s8b af[2], bf[2];
#pragma unroll
                for (int i = 0; i < 2; ++i)
                    af[i] = *(const s8b*)&As[hh][(wm * 64 + i * 32 + l31) * 32 + koff];
#pragma unroll
                for (int j = 0; j < 2; ++j)
                    bf[j] = *(const s8b*)&Bs[hh][(wn * 64 + j * 32 + l31) * 32 + koff];
#pragma unroll
                for (int i = 0; i < 2; ++i)
#pragma unroll
                    for (int j = 0; j < 2; ++j)
                        acc[i][j] = __builtin_amdgcn_mfma_f32_32x32x16_bf16(
                            af[i], bf[j], acc[i][j], 0, 0, 0);
            }
        }
        __syncthreads();
    }

    float bias[2];
#pragma unroll
    for (int j = 0; j < 2; ++j) bias[j] = db[bn + wn * 64 + j * 32 + l31];
#pragma unroll
    for (int i = 0; i < 2; ++i) {
#pragma unroll
        for (int r = 0; r < 16; ++r) {
            int row = bm + wm * 64 + i * 32 + (r & 3) + 8 * (r >> 2) + 4 * lh;
            if (row < BW_) {
#pragma unroll
                for (int j = 0; j < 2; ++j) {
                    int cn = bn + wn * 64 + j * 32 + l31;
                    h[(size_t)row * D_ + cn] =
                        f2bf(fast_tanh(acc[i][j][r] + bias[j]));
                }
            }
        }
    }
}

// ---------------------------------------------------------------------------
// K5: [wcl | bin] = h . Bcat^T + bias via MFMA 16x16x32. Barrier-free:
// A frags direct from h (L3-resident), B frags from L2-hot Bcat.
// ---------------------------------------------------------------------------
__global__ __launch_bounds__(256) void k_gemm2(const short* __restrict__ h,
                                               const short* __restrict__ Bcat,
                                               const float* __restrict__ ob,
                                               const float* __restrict__ beff,
                                               float* __restrict__ out) {
    int tid  = threadIdx.x;
    int lane = tid & 63;
    int w    = tid >> 6;
    int ln = lane & 15, qk = lane >> 4;
    int m0 = blockIdx.x * 64 + w * 16;

    int arow = m0 + ln;
    arow = arow < BW_ ? arow : BW_ - 1;
    const short* ap = h + (size_t)arow * D_ + qk * 8;
    const short* bp = Bcat + (size_t)ln * D_ + qk * 8;

    f32x4 acc[6];
#pragma unroll
    for (int j = 0; j < 6; ++j) acc[j] = (f32x4){0.f, 0.f, 0.f, 0.f};

#pragma unroll 4
    for (int kt = 0; kt < D_; kt += 32) {
        s8b af = *(const s8b*)(ap + kt);
        s8b bf[6];
#pragma unroll
        for (int j = 0; j < 6; ++j)
            bf[j] = *(const s8b*)(bp + (size_t)j * 16 * D_ + kt);
#pragma unroll
        for (int j = 0; j < 6; ++j)
            acc[j] = __builtin_amdgcn_mfma_f32_16x16x32_bf16(af, bf[j], acc[j], 0, 0, 0);
    }

    float bj[6];
#pragma unroll
    for (int j = 0; j < 6; ++j) {
        int c = j * 16 + ln;
        bj[j] = (c < NMUT) ? ob[c] : beff[c - NMUT];
    }
#pragma unroll
    for (int r = 0; r < 4; ++r) {
        int row = m0 + qk * 4 + r;
        if (row < BW_) {
#pragma unroll
            for (int j = 0; j < 6; ++j) {
                int c = j * 16 + ln;
                float v = acc[j][r] + bj[j];
                if (c < NMUT) out[(size_t)row * NMUT + c] = v;
                else out[(size_t)BW_ * NMUT + (size_t)row * NBIN + (c - NMUT)] = v;
            }
        }
    }
}

// ---------------------------------------------------------------------------
extern "C" void kernel_launch(void* const* d_in, const int* in_sizes, int n_in,
                              void* d_out, int out_size, void* d_ws, size_t ws_size,
                              hipStream_t stream) {
    const float* feat    = (const float*)d_in[0];
    const int*   wstarts = (const int*)d_in[1];
    const float* dw      = (const float*)d_in[2];
    const float* db      = (const float*)d_in[3];
    const float* ow      = (const float*)d_in[4];
    const float* ob      = (const float*)d_in[5];
    const float* bw      = (const float*)d_in[6];
    const float* bb      = (const float*)d_in[7];
    float* out = (float*)d_out;

    char* ws = (char*)d_ws;
    size_t off = 0;
    auto alloc = [&](size_t bytes) {
        void* p = ws + off;
        off += (bytes + 255) & ~(size_t)255;
        return p;
    };
    short* wf     = (short*)alloc((size_t)BW_ * D_ * 2);
    short* h      = (short*)alloc((size_t)BW_ * D_ * 2);
    short* dwb    = (short*)alloc((size_t)D_ * D_ * 2);
    short* Bcat   = (short*)alloc((size_t)(NMUT + NBIN) * D_ * 2);
    float* beff   = (float*)alloc(NBIN * 4);
    int*   starts = (int*)alloc((size_t)B_ * (W_ + 1) * 4);
    int*   nwords = (int*)alloc(B_ * 4);

    k_prep<<<1136, 256, 0, stream>>>(wstarts, dw, ow, ob, bw, bb,
                                     starts, nwords, dwb, Bcat, beff);
    k_wf<<<BW_ / 2, 256, 0, stream>>>(feat, starts, nwords, wf);
    k_gemm1<<<dim3((BW_ + 127) / 128, D_ / 128), 256, 0, stream>>>(wf, dwb, db, h);
    k_gemm2<<<(BW_ + 63) / 64, 256, 0, stream>>>(h, Bcat, ob, beff, out);
}